// Round 4
// baseline (208.574 us; speedup 1.0000x reference)
//
#include <hip/hip_runtime.h>
#include <stdint.h>

#define HWPOS 1024
#define CCH   256
#define RROWS 128   // 2B
#define EPSF  1.1920928955078125e-07f

typedef __attribute__((ext_vector_type(8))) short   short8;
typedef __attribute__((ext_vector_type(4))) float   float4v;

__device__ __forceinline__ unsigned short f2bf(float f) {
  uint32_t x = __float_as_uint(f);
  x += 0x7FFFu + ((x >> 16) & 1u);          // RNE bf16
  return (unsigned short)(x >> 16);
}

// ws layout (16B-chunk units): addr16(hw,half,r,s) = hw*4096 + half*2048 + r*16 + s
//   half = c-chunk group (0: c<128, 1: c>=128), r = row 0..127, s = swizzled
//   slot-in-half 0..15 (data chunk c8 stored at low3(c8)^(r&7) within its 8-group).

// ---------------------------------------------------------------------------
// Kernel 1 (v3): transpose [B,C,H,W] f32 -> ws bf16 (layout above).
// Block = one r x 32 hw x all 256 c. Lane: 8 float4 loads (8 c at 4KB stride,
// 4 hw each). Per wave-instruction: 8 FULL 128B granules.
// ---------------------------------------------------------------------------
__global__ __launch_bounds__(256) void k_transpose(const float* __restrict__ inp,
                                                   const float* __restrict__ tgt,
                                                   unsigned short* __restrict__ wsF) {
  const int t   = threadIdx.x;
  const int j   = t & 7;          // chunk-within-group
  const int h4  = (t >> 3) & 7;   // hw quad index (4 hw each)
  const int g   = t >> 6;         // wave id = chunk group (0..3)
  const int r   = blockIdx.y;
  const int hw0 = blockIdx.x * 32;
  const int m   = r & 7;
  const int slot   = g * 8 + j;         // destination 16B chunk (0..31)
  const int c8     = g * 8 + (j ^ m);   // source data chunk
  const int halfIx = slot >> 4;
  const int slotIn = slot & 15;
  const float* src = (r < 64) ? (inp + (size_t)r * CCH * HWPOS)
                              : (tgt + (size_t)(r - 64) * CCH * HWPOS);
  const float* p = src + (size_t)c8 * 8 * HWPOS + hw0 + h4 * 4;
  float4 v[8];
#pragma unroll
  for (int e = 0; e < 8; ++e) v[e] = *(const float4*)(p + (size_t)e * HWPOS);
  uint4 o[4];
#pragma unroll
  for (int q = 0; q < 4; ++q) {
    float s0 = (q == 0) ? v[0].x : (q == 1) ? v[0].y : (q == 2) ? v[0].z : v[0].w;
    float s1 = (q == 0) ? v[1].x : (q == 1) ? v[1].y : (q == 2) ? v[1].z : v[1].w;
    float s2 = (q == 0) ? v[2].x : (q == 1) ? v[2].y : (q == 2) ? v[2].z : v[2].w;
    float s3 = (q == 0) ? v[3].x : (q == 1) ? v[3].y : (q == 2) ? v[3].z : v[3].w;
    float s4 = (q == 0) ? v[4].x : (q == 1) ? v[4].y : (q == 2) ? v[4].z : v[4].w;
    float s5 = (q == 0) ? v[5].x : (q == 1) ? v[5].y : (q == 2) ? v[5].z : v[5].w;
    float s6 = (q == 0) ? v[6].x : (q == 1) ? v[6].y : (q == 2) ? v[6].z : v[6].w;
    float s7 = (q == 0) ? v[7].x : (q == 1) ? v[7].y : (q == 2) ? v[7].z : v[7].w;
    o[q].x = f2bf(s0) | ((uint32_t)f2bf(s1) << 16);
    o[q].y = f2bf(s2) | ((uint32_t)f2bf(s3) << 16);
    o[q].z = f2bf(s4) | ((uint32_t)f2bf(s5) << 16);
    o[q].w = f2bf(s6) | ((uint32_t)f2bf(s7) << 16);
  }
#pragma unroll
  for (int q = 0; q < 4; ++q) {
    const size_t a16 = (size_t)(hw0 + h4 * 4 + q) * 4096 + halfIx * 2048 + r * 16 + slotIn;
    *(uint4*)(wsF + a16 * 8) = o[q];
  }
}

// ---------------------------------------------------------------------------
// Kernel 2 (v2): one block per hw, LDS cut to 32KB via K-split: stage c-half,
// MFMA over it, restage other half. 8 waves; wave w owns row-tile w x 8 cols.
// LDS ~33KB -> 4 blocks/CU (was 65KB > 64KB/WG boundary -> near-serial
// dispatch, Occupancy 0.48%).
// ---------------------------------------------------------------------------
__global__ __launch_bounds__(512, 8) void k_gram(const unsigned short* __restrict__ wsF,
                                                 float* __restrict__ partials) {
  __shared__ unsigned short Fs[RROWS * 128];   // 32 KB, one c-half, swizzled
  __shared__ float sInv[RROWS];
  __shared__ float wred[8];
  const int t  = threadIdx.x;
  const int hw = blockIdx.x;
  const int lane = t & 63;
  const int w    = t >> 6;        // wave id 0..7 = row-tile
  const int lid  = lane & 15;
  const int quad = lane >> 4;
  const int lm   = lid & 7;       // r&7 for every row this lane touches
  float4v acc[8];
#pragma unroll
  for (int ni = 0; ni < 8; ++ni) acc[ni] = (float4v){0.f, 0.f, 0.f, 0.f};
  const int rowA = ((w << 4) | lid) * 128;
  const unsigned short* gsrc = wsF + (size_t)hw * 65536;  // shorts per hw
#pragma unroll
  for (int half = 0; half < 2; ++half) {
    // stage 32KB half: contiguous, direct global->LDS DMA, 16B/lane
#pragma unroll
    for (int it = 0; it < 4; ++it) {
      const size_t ch = (size_t)it * 512 + t;
      __builtin_amdgcn_global_load_lds(
          (const __attribute__((address_space(1))) unsigned int*)(gsrc + (size_t)half * 32768 + ch * 8),
          (__attribute__((address_space(3))) unsigned int*)(Fs + ch * 8),
          16, 0, 0);
    }
    __syncthreads();
#pragma unroll
    for (int ks = 0; ks < 4; ++ks) {
      const int off = (((ks * 4 + quad) ^ lm) << 3);   // swizzled slot offset
      short8 a = *(const short8*)&Fs[rowA + off];
#pragma unroll
      for (int ni = 0; ni < 8; ++ni) {
        short8 b = *(const short8*)&Fs[((ni << 4) | lid) * 128 + off];
        acc[ni] = __builtin_amdgcn_mfma_f32_16x16x32_bf16(a, b, acc[ni], 0, 0, 0);
      }
    }
    __syncthreads();   // before overwriting Fs with next half
  }
  // inverse norms from diag (tile ni==w; lanes with lid>>2 == quad hold it)
  if ((lid >> 2) == quad) {
    float nrm = fmaxf(sqrtf(acc[w][lid & 3]), EPSF);
    sInv[(w << 4) | lid] = 1.0f / nrm;
  }
  __syncthreads();
  float invj[8];
#pragma unroll
  for (int ni = 0; ni < 8; ++ni) invj[ni] = sInv[(ni << 4) | lid];
  float lacc = 0.f;
#pragma unroll
  for (int reg = 0; reg < 4; ++reg) {
    const int rloc = quad * 4 + reg;           // local row in tile
    const int rg   = (w << 4) | rloc;          // global row 0..127
    const float invi = sInv[rg];
    float v[8];
#pragma unroll
    for (int ni = 0; ni < 8; ++ni) v[ni] = 2.0f * acc[ni][reg] * invi * invj[ni];
    if (lid == rloc) v[w] = -3.0e38f;          // mask self-similarity
    float mx = v[0];
#pragma unroll
    for (int ni = 1; ni < 8; ++ni) mx = fmaxf(mx, v[ni]);
#pragma unroll
    for (int s = 1; s < 16; s <<= 1) mx = fmaxf(mx, __shfl_xor(mx, s, 16));
    float sm = 0.f;
#pragma unroll
    for (int ni = 0; ni < 8; ++ni) sm += __expf(v[ni] - mx);
#pragma unroll
    for (int s = 1; s < 16; s <<= 1) sm += __shfl_xor(sm, s, 16);
    const float lse = mx + __logf(sm);
    const int jp = (rg + 64) & 127;            // positive-pair column
    const float cand = v[jp >> 4];
    const float vp = __shfl(cand, jp & 15, 16);
    lacc += vp - lse;                          // log_softmax at partner (x16 lanes)
  }
#pragma unroll
  for (int s = 1; s < 64; s <<= 1) lacc += __shfl_xor(lacc, s, 64);
  if (lane == 0) wred[w] = lacc;
  __syncthreads();
  if (t == 0) {
    float tot = 0.f;
#pragma unroll
    for (int i = 0; i < 8; ++i) tot += wred[i];
    partials[hw] = tot;                        // = 16 * sum_rows(pos) for this hw
  }
}

// ---------------------------------------------------------------------------
// Kernel 3: reduce 1024 partials -> scalar loss
// ---------------------------------------------------------------------------
__global__ __launch_bounds__(256) void k_reduce(const float* __restrict__ partials,
                                                float* __restrict__ out) {
  __shared__ float wr[4];
  const int t = threadIdx.x;
  float s = 0.f;
#pragma unroll
  for (int i = 0; i < 4; ++i) s += partials[t + i * 256];
#pragma unroll
  for (int sh = 1; sh < 64; sh <<= 1) s += __shfl_xor(s, sh, 64);
  if ((t & 63) == 0) wr[t >> 6] = s;
  __syncthreads();
  if (t == 0) {
    out[0] = -(wr[0] + wr[1] + wr[2] + wr[3]) / (131072.0f * 16.0f);
  }
}

extern "C" void kernel_launch(void* const* d_in, const int* in_sizes, int n_in,
                              void* d_out, int out_size, void* d_ws, size_t ws_size,
                              hipStream_t stream) {
  const float* inp = (const float*)d_in[0];
  const float* tgt = (const float*)d_in[1];
  unsigned short* wsF = (unsigned short*)d_ws;
  float* partials = (float*)((char*)d_ws + (size_t)HWPOS * RROWS * CCH * 2);
  k_transpose<<<dim3(32, 128), 256, 0, stream>>>(inp, tgt, wsF);
  k_gram<<<dim3(HWPOS), 512, 0, stream>>>(wsF, partials);
  k_reduce<<<1, 256, 0, stream>>>(partials, (float*)d_out);
}

// Round 5
// 181.708 us; speedup vs baseline: 1.1479x; 1.1479x over previous
//
#include <hip/hip_runtime.h>
#include <stdint.h>

#define HWPOS 1024
#define CCH   256
#define RROWS 128   // 2B
#define EPSF  1.1920928955078125e-07f

typedef __attribute__((ext_vector_type(8))) short   short8;
typedef __attribute__((ext_vector_type(4))) float   float4v;

__device__ __forceinline__ unsigned short f2bf(float f) {
  uint32_t x = __float_as_uint(f);
  x += 0x7FFFu + ((x >> 16) & 1u);          // RNE bf16
  return (unsigned short)(x >> 16);
}

// ws layout (16B-chunk units): addr16(hw,half,r,s) = hw*4096 + half*2048 + r*16 + s
//   half = c-chunk group (0: c<128, 1: c>=128), r = row 0..127, s = swizzled
//   slot-in-half 0..15 (data chunk c8 stored at low3(c8)^(r&7) within its 8-group).

// ---------------------------------------------------------------------------
// Kernel 1 (v3): transpose [B,C,H,W] f32 -> ws bf16 (layout above).
// Block = one r x 32 hw x all 256 c. Lane: 8 float4 loads (8 c at 4KB stride,
// 4 hw each). Per wave-instruction: 8 FULL 128B granules.
// ---------------------------------------------------------------------------
__global__ __launch_bounds__(256) void k_transpose(const float* __restrict__ inp,
                                                   const float* __restrict__ tgt,
                                                   unsigned short* __restrict__ wsF) {
  const int t   = threadIdx.x;
  const int j   = t & 7;          // chunk-within-group
  const int h4  = (t >> 3) & 7;   // hw quad index (4 hw each)
  const int g   = t >> 6;         // wave id = chunk group (0..3)
  const int r   = blockIdx.y;
  const int hw0 = blockIdx.x * 32;
  const int m   = r & 7;
  const int slot   = g * 8 + j;         // destination 16B chunk (0..31)
  const int c8     = g * 8 + (j ^ m);   // source data chunk
  const int halfIx = slot >> 4;
  const int slotIn = slot & 15;
  const float* src = (r < 64) ? (inp + (size_t)r * CCH * HWPOS)
                              : (tgt + (size_t)(r - 64) * CCH * HWPOS);
  const float* p = src + (size_t)c8 * 8 * HWPOS + hw0 + h4 * 4;
  float4 v[8];
#pragma unroll
  for (int e = 0; e < 8; ++e) v[e] = *(const float4*)(p + (size_t)e * HWPOS);
  uint4 o[4];
#pragma unroll
  for (int q = 0; q < 4; ++q) {
    float s0 = (q == 0) ? v[0].x : (q == 1) ? v[0].y : (q == 2) ? v[0].z : v[0].w;
    float s1 = (q == 0) ? v[1].x : (q == 1) ? v[1].y : (q == 2) ? v[1].z : v[1].w;
    float s2 = (q == 0) ? v[2].x : (q == 1) ? v[2].y : (q == 2) ? v[2].z : v[2].w;
    float s3 = (q == 0) ? v[3].x : (q == 1) ? v[3].y : (q == 2) ? v[3].z : v[3].w;
    float s4 = (q == 0) ? v[4].x : (q == 1) ? v[4].y : (q == 2) ? v[4].z : v[4].w;
    float s5 = (q == 0) ? v[5].x : (q == 1) ? v[5].y : (q == 2) ? v[5].z : v[5].w;
    float s6 = (q == 0) ? v[6].x : (q == 1) ? v[6].y : (q == 2) ? v[6].z : v[6].w;
    float s7 = (q == 0) ? v[7].x : (q == 1) ? v[7].y : (q == 2) ? v[7].z : v[7].w;
    o[q].x = f2bf(s0) | ((uint32_t)f2bf(s1) << 16);
    o[q].y = f2bf(s2) | ((uint32_t)f2bf(s3) << 16);
    o[q].z = f2bf(s4) | ((uint32_t)f2bf(s5) << 16);
    o[q].w = f2bf(s6) | ((uint32_t)f2bf(s7) << 16);
  }
#pragma unroll
  for (int q = 0; q < 4; ++q) {
    const size_t a16 = (size_t)(hw0 + h4 * 4 + q) * 4096 + halfIx * 2048 + r * 16 + slotIn;
    *(uint4*)(wsF + a16 * 8) = o[q];
  }
}

// ---------------------------------------------------------------------------
// Kernel 2 (v3): one block per hw, 32KB K-split staging. 8 waves; wave w owns
// row-tile w x 8 col-tiles. SCRATCH FIX: no dynamic indexing into register
// arrays (acc[w], v[w], v[jp>>4] in earlier versions forced a 64KB/block
// scratch round-trip -> scratch-pool dispatch throttle -> 0.5% occupancy).
// All selects are unrolled; tile indices involved are wave-uniform.
// ---------------------------------------------------------------------------
__global__ __launch_bounds__(512, 4) void k_gram(const unsigned short* __restrict__ wsF,
                                                 float* __restrict__ partials) {
  __shared__ unsigned short Fs[RROWS * 128];   // 32 KB, one c-half, swizzled
  __shared__ float sInv[RROWS];
  __shared__ float wred[8];
  const int t  = threadIdx.x;
  const int hw = blockIdx.x;
  const int lane = t & 63;
  const int w    = t >> 6;        // wave id 0..7 = row-tile
  const int lid  = lane & 15;
  const int quad = lane >> 4;
  const int lm   = lid & 7;       // r&7 for every row this lane touches
  float4v acc[8];
#pragma unroll
  for (int ni = 0; ni < 8; ++ni) acc[ni] = (float4v){0.f, 0.f, 0.f, 0.f};
  const int rowA = ((w << 4) | lid) * 128;
  const unsigned short* gsrc = wsF + (size_t)hw * 65536;  // shorts per hw
#pragma unroll
  for (int half = 0; half < 2; ++half) {
    // stage 32KB half: contiguous, direct global->LDS DMA, 16B/lane
#pragma unroll
    for (int it = 0; it < 4; ++it) {
      const size_t ch = (size_t)it * 512 + t;
      __builtin_amdgcn_global_load_lds(
          (const __attribute__((address_space(1))) unsigned int*)(gsrc + (size_t)half * 32768 + ch * 8),
          (__attribute__((address_space(3))) unsigned int*)(Fs + ch * 8),
          16, 0, 0);
    }
    __syncthreads();
#pragma unroll
    for (int ks = 0; ks < 4; ++ks) {
      const int off = (((ks * 4 + quad) ^ lm) << 3);   // swizzled slot offset
      short8 a = *(const short8*)&Fs[rowA + off];
#pragma unroll
      for (int ni = 0; ni < 8; ++ni) {
        short8 b = *(const short8*)&Fs[((ni << 4) | lid) * 128 + off];
        acc[ni] = __builtin_amdgcn_mfma_f32_16x16x32_bf16(a, b, acc[ni], 0, 0, 0);
      }
    }
    __syncthreads();   // before overwriting Fs with next half
  }
  // diagonal extract WITHOUT dynamic indexing: tile w (uniform), elem lid&3
  {
    float diagv = 0.f;
#pragma unroll
    for (int ni = 0; ni < 8; ++ni) {
      if (ni == w) {
#pragma unroll
        for (int e = 0; e < 4; ++e)
          if (e == (lid & 3)) diagv = acc[ni][e];
      }
    }
    if ((lid >> 2) == quad) {
      sInv[(w << 4) | lid] = 1.0f / fmaxf(sqrtf(diagv), EPSF);
    }
  }
  __syncthreads();
  float invj[8];
#pragma unroll
  for (int ni = 0; ni < 8; ++ni) invj[ni] = sInv[(ni << 4) | lid];
  const int tj = (w + 4) & 7;     // partner col-tile (wave-uniform)
  float lacc = 0.f;
#pragma unroll
  for (int reg = 0; reg < 4; ++reg) {
    const int rloc = quad * 4 + reg;           // local row in tile
    const int rg   = (w << 4) | rloc;          // global row 0..127
    const float invi = sInv[rg];
    float v[8];
#pragma unroll
    for (int ni = 0; ni < 8; ++ni) v[ni] = 2.0f * acc[ni][reg] * invi * invj[ni];
    // mask self-similarity: tile w (uniform), column rloc
#pragma unroll
    for (int ni = 0; ni < 8; ++ni)
      if (ni == w && lid == rloc) v[ni] = -3.0e38f;
    float mx = v[0];
#pragma unroll
    for (int ni = 1; ni < 8; ++ni) mx = fmaxf(mx, v[ni]);
#pragma unroll
    for (int s = 1; s < 16; s <<= 1) mx = fmaxf(mx, __shfl_xor(mx, s, 16));
    float sm = 0.f;
#pragma unroll
    for (int ni = 0; ni < 8; ++ni) sm += __expf(v[ni] - mx);
#pragma unroll
    for (int s = 1; s < 16; s <<= 1) sm += __shfl_xor(sm, s, 16);
    const float lse = mx + __logf(sm);
    // positive pair: col jp=(rg+64)&127 -> tile tj (uniform), lane rloc
    float cand = 0.f;
#pragma unroll
    for (int ni = 0; ni < 8; ++ni)
      if (ni == tj) cand = v[ni];
    const float vp = __shfl(cand, rloc, 16);
    lacc += vp - lse;                          // log_softmax at partner (x16 lanes)
  }
#pragma unroll
  for (int s = 1; s < 64; s <<= 1) lacc += __shfl_xor(lacc, s, 64);
  if (lane == 0) wred[w] = lacc;
  __syncthreads();
  if (t == 0) {
    float tot = 0.f;
#pragma unroll
    for (int i = 0; i < 8; ++i) tot += wred[i];
    partials[hw] = tot;                        // = 16 * sum_rows(pos) for this hw
  }
}

// ---------------------------------------------------------------------------
// Kernel 3: reduce 1024 partials -> scalar loss
// ---------------------------------------------------------------------------
__global__ __launch_bounds__(256) void k_reduce(const float* __restrict__ partials,
                                                float* __restrict__ out) {
  __shared__ float wr[4];
  const int t = threadIdx.x;
  float s = 0.f;
#pragma unroll
  for (int i = 0; i < 4; ++i) s += partials[t + i * 256];
#pragma unroll
  for (int sh = 1; sh < 64; sh <<= 1) s += __shfl_xor(s, sh, 64);
  if ((t & 63) == 0) wr[t >> 6] = s;
  __syncthreads();
  if (t == 0) {
    out[0] = -(wr[0] + wr[1] + wr[2] + wr[3]) / (131072.0f * 16.0f);
  }
}

extern "C" void kernel_launch(void* const* d_in, const int* in_sizes, int n_in,
                              void* d_out, int out_size, void* d_ws, size_t ws_size,
                              hipStream_t stream) {
  const float* inp = (const float*)d_in[0];
  const float* tgt = (const float*)d_in[1];
  unsigned short* wsF = (unsigned short*)d_ws;
  float* partials = (float*)((char*)d_ws + (size_t)HWPOS * RROWS * CCH * 2);
  k_transpose<<<dim3(32, 128), 256, 0, stream>>>(inp, tgt, wsF);
  k_gram<<<dim3(HWPOS), 512, 0, stream>>>(wsF, partials);
  k_reduce<<<1, 256, 0, stream>>>(partials, (float*)d_out);
}